// Round 1
// baseline (1278.435 us; speedup 1.0000x reference)
//
#include <hip/hip_runtime.h>
#include <math.h>

#define B_ 16
#define S_ 4096
#define E_ 1024
#define H_ 512

#define S_TILE 32
#define KT 16

// dp[b][h] = sum_e dec[b][e] * Wd[e][h] + bd[h] + be[h]
// (bo dropped: softmax-invariant)
__global__ __launch_bounds__(256) void dp_kernel(const float* __restrict__ dec,
                                                 const float* __restrict__ Wd,
                                                 const float* __restrict__ bd,
                                                 const float* __restrict__ be,
                                                 float* __restrict__ dp) {
    int h = blockIdx.x * 16 + (threadIdx.x & 15);
    int b = threadIdx.x >> 4;
    const float* drow = dec + b * E_;
    float acc = 0.f;
    for (int e = 0; e < E_; ++e)
        acc = fmaf(drow[e], Wd[(size_t)e * H_ + h], acc);
    dp[b * H_ + h] = acc + bd[h] + be[h];
}

// scores[b][s] = sum_h tanh( (enc[b,s,:] . We[:,h]) + dp[b][h] ) * Wo[h]
// Block: one (b, 32-row s-tile), covers all H=512.
// Thread tile: 8 s x 8 h (h strided by 64 so wave lanes cover h contiguously).
__global__ __launch_bounds__(256) void scores_kernel(
    const float* __restrict__ enc, const float* __restrict__ We,
    const float* __restrict__ Wo, const float* __restrict__ dp,
    float* __restrict__ scores) {
    __shared__ float sWe[KT][H_];       // 32 KB
    __shared__ float sEnc[S_TILE][KT];  // 2 KB
    int b = blockIdx.x >> 7;
    int st = blockIdx.x & 127;
    int s_base = st * S_TILE;
    int tid = threadIdx.x;
    int gh = tid & 63;   // lane: h = gh + 64*j
    int gs = tid >> 6;   // wave: s = s_base + gs*8 + i
    float acc[8][8];
#pragma unroll
    for (int i = 0; i < 8; ++i)
#pragma unroll
        for (int j = 0; j < 8; ++j) acc[i][j] = 0.f;

    const float* encB = enc + ((size_t)b * S_ + s_base) * E_;

    for (int k0 = 0; k0 < E_; k0 += KT) {
        __syncthreads();
        // stage We[k0:k0+16][0:512] : 2048 float4, 8 per thread, coalesced
#pragma unroll
        for (int r = 0; r < 8; ++r) {
            int t4 = tid + 256 * r;
            int row = t4 >> 7;
            int c4 = (t4 & 127) << 2;
            *(float4*)(&sWe[row][c4]) =
                *(const float4*)(We + (size_t)(k0 + row) * H_ + c4);
        }
        // stage enc tile: 32 s x 16 k = 128 float4, threads 0..127
        if (tid < 128) {
            int s = tid >> 2;
            int kk = (tid & 3) << 2;
            float4 v = *(const float4*)(encB + (size_t)s * E_ + k0 + kk);
            sEnc[s][kk] = v.x; sEnc[s][kk + 1] = v.y;
            sEnc[s][kk + 2] = v.z; sEnc[s][kk + 3] = v.w;
        }
        __syncthreads();
#pragma unroll 4
        for (int k = 0; k < KT; ++k) {
            float a[8], bb[8];
#pragma unroll
            for (int i = 0; i < 8; ++i) a[i] = sEnc[gs * 8 + i][k];   // broadcast
#pragma unroll
            for (int j = 0; j < 8; ++j) bb[j] = sWe[k][gh + 64 * j];  // stride-1 lanes
#pragma unroll
            for (int i = 0; i < 8; ++i)
#pragma unroll
                for (int j = 0; j < 8; ++j)
                    acc[i][j] = fmaf(a[i], bb[j], acc[i][j]);
        }
    }

    // epilogue: tanh + Wo dot + wave reduction over h
    float dpv[8], wov[8];
    const float* dpb = dp + b * H_;
#pragma unroll
    for (int j = 0; j < 8; ++j) {
        int h = gh + 64 * j;
        dpv[j] = dpb[h];
        wov[j] = Wo[h];
    }
#pragma unroll
    for (int i = 0; i < 8; ++i) {
        float sum = 0.f;
#pragma unroll
        for (int j = 0; j < 8; ++j)
            sum += tanhf(acc[i][j] + dpv[j]) * wov[j];
        for (int off = 32; off; off >>= 1) sum += __shfl_xor(sum, off, 64);
        if (gh == 0)
            scores[(size_t)b * S_ + s_base + gs * 8 + i] = sum;
    }
}

// in-place softmax over S=4096 per batch row
__global__ __launch_bounds__(256) void softmax_kernel(float* __restrict__ sc) {
    int b = blockIdx.x;
    float* row = sc + (size_t)b * S_;
    int tid = threadIdx.x;
    float v[16];
    float m = -1e30f;
#pragma unroll
    for (int i = 0; i < 16; ++i) {
        v[i] = row[i * 256 + tid];
        m = fmaxf(m, v[i]);
    }
    for (int off = 32; off; off >>= 1) m = fmaxf(m, __shfl_xor(m, off, 64));
    __shared__ float redm[4];
    __shared__ float reds[4];
    if ((tid & 63) == 0) redm[tid >> 6] = m;
    __syncthreads();
    m = fmaxf(fmaxf(redm[0], redm[1]), fmaxf(redm[2], redm[3]));
    float s = 0.f;
#pragma unroll
    for (int i = 0; i < 16; ++i) {
        v[i] = expf(v[i] - m);
        s += v[i];
    }
    for (int off = 32; off; off >>= 1) s += __shfl_xor(s, off, 64);
    if ((tid & 63) == 0) reds[tid >> 6] = s;
    __syncthreads();
    s = reds[0] + reds[1] + reds[2] + reds[3];
    float inv = 1.f / s;
#pragma unroll
    for (int i = 0; i < 16; ++i) row[i * 256 + tid] = v[i] * inv;
}

__global__ __launch_bounds__(256) void zero_kernel(float* __restrict__ out) {
    out[blockIdx.x * 256 + threadIdx.x] = 0.f;
}

// context[b][e] = sum_s attn[b][s] * enc[b][s][e]
// block = (b, 128-row s-chunk); thread owns 4 e-columns (float4); atomic combine.
__global__ __launch_bounds__(256) void ctx_kernel(const float* __restrict__ enc,
                                                  const float* __restrict__ attn,
                                                  float* __restrict__ out) {
    int b = blockIdx.x >> 5;
    int s0 = (blockIdx.x & 31) * 128;
    int tid = threadIdx.x;
    __shared__ float w[128];
    if (tid < 128) w[tid] = attn[(size_t)b * S_ + s0 + tid];
    __syncthreads();
    const float* base = enc + ((size_t)b * S_ + s0) * E_ + tid * 4;
    float4 acc = make_float4(0.f, 0.f, 0.f, 0.f);
    for (int s = 0; s < 128; ++s) {
        float4 v = *(const float4*)(base + (size_t)s * E_);
        float ws = w[s];
        acc.x = fmaf(ws, v.x, acc.x);
        acc.y = fmaf(ws, v.y, acc.y);
        acc.z = fmaf(ws, v.z, acc.z);
        acc.w = fmaf(ws, v.w, acc.w);
    }
    float* o = out + b * E_ + tid * 4;
    atomicAdd(o + 0, acc.x);
    atomicAdd(o + 1, acc.y);
    atomicAdd(o + 2, acc.z);
    atomicAdd(o + 3, acc.w);
}

extern "C" void kernel_launch(void* const* d_in, const int* in_sizes, int n_in,
                              void* d_out, int out_size, void* d_ws, size_t ws_size,
                              hipStream_t stream) {
    const float* enc = (const float*)d_in[0];  // [16,4096,1024]
    const float* dec = (const float*)d_in[1];  // [16,1024]
    const float* We  = (const float*)d_in[2];  // [1024,512]
    const float* be  = (const float*)d_in[3];  // [512]
    const float* Wd  = (const float*)d_in[4];  // [1024,512]
    const float* bd  = (const float*)d_in[5];  // [512]
    const float* Wo  = (const float*)d_in[6];  // [512,1]
    // d_in[7] = bo: softmax-invariant, unused.
    float* out = (float*)d_out;                // [16,1024]

    float* dp = (float*)d_ws;                  // [16][512]
    float* scores = dp + B_ * H_;              // [16][4096], softmax in-place

    dp_kernel<<<H_ / 16, 256, 0, stream>>>(dec, Wd, bd, be, dp);
    scores_kernel<<<B_ * (S_ / S_TILE), 256, 0, stream>>>(enc, We, Wo, dp, scores);
    softmax_kernel<<<B_, 256, 0, stream>>>(scores);
    zero_kernel<<<(B_ * E_) / 256, 256, 0, stream>>>(out);
    ctx_kernel<<<B_ * 32, 256, 0, stream>>>(enc, scores, out);
}

// Round 2
// 539.561 us; speedup vs baseline: 2.3694x; 2.3694x over previous
//
#include <hip/hip_runtime.h>
#include <hip/hip_bf16.h>
#include <math.h>

#define B_ 16
#define S_ 4096
#define E_ 1024
#define H_ 512

typedef short bf16x8 __attribute__((ext_vector_type(8)));
typedef unsigned short u16x8 __attribute__((ext_vector_type(8)));
typedef float f32x4 __attribute__((ext_vector_type(4)));

__device__ inline unsigned short f2bf(float x) {
    __hip_bfloat16 h = __float2bfloat16(x);
    return *(unsigned short*)&h;
}

// WeT[n][k] = bf16(We[k][n]);  64x64 LDS transpose tiles.
__global__ __launch_bounds__(256) void we_transpose_kernel(
    const float* __restrict__ We, unsigned short* __restrict__ WeT) {
    __shared__ float sT[64][65];
    int k0 = (blockIdx.x >> 3) * 64;  // 16 k-tiles
    int n0 = (blockIdx.x & 7) * 64;   // 8 n-tiles
    int t = threadIdx.x;
#pragma unroll
    for (int p = 0; p < 16; ++p) {
        int idx = p * 256 + t;
        int k = idx >> 6, n = idx & 63;
        sT[n][k] = We[(size_t)(k0 + k) * H_ + n0 + n];
    }
    __syncthreads();
#pragma unroll
    for (int p = 0; p < 16; ++p) {
        int idx = p * 256 + t;
        int n = idx >> 6, k = idx & 63;
        WeT[(size_t)(n0 + n) * E_ + k0 + k] = f2bf(sT[n][k]);
    }
}

// dp[b][h] = dec[b,:] . Wd[:,h] + bd[h] + be[h]   (bo dropped: softmax-invariant)
// grid = 16 b x 8 h-chunks; thread: (h = hc*64 + t&63, e-quarter = t>>6)
__global__ __launch_bounds__(256) void dp_kernel(const float* __restrict__ dec,
                                                 const float* __restrict__ Wd,
                                                 const float* __restrict__ bd,
                                                 const float* __restrict__ be,
                                                 float* __restrict__ dp) {
    int b = blockIdx.x >> 3;
    int hc = blockIdx.x & 7;
    int t = threadIdx.x;
    int h = hc * 64 + (t & 63);
    int ec = t >> 6;
    const float* dr = dec + b * E_ + ec * 256;
    const float* wp = Wd + (size_t)(ec * 256) * H_ + h;
    float acc = 0.f;
#pragma unroll 8
    for (int e = 0; e < 256; ++e) acc = fmaf(dr[e], wp[(size_t)e * H_], acc);
    __shared__ float red[4][64];
    red[ec][t & 63] = acc;
    __syncthreads();
    if (t < 64) {
        int hh = hc * 64 + t;
        dp[b * H_ + hh] = red[0][t] + red[1][t] + red[2][t] + red[3][t] + bd[hh] + be[hh];
    }
}

// scores partial: parts[nt][b][s] = sum_{h in 128-chunk nt} tanh(enc@We + dp) * Wo
// Block: 128 s-rows x 128 h-cols, K staged in 32-chunks. MFMA 16x16x32 bf16.
#define BM 128
#define BN 128
#define BK 32
#define LDA 40  // padded row (shorts): 80 B stride -> 2-way-only conflicts

__global__ __launch_bounds__(256) void scores_mfma_kernel(
    const float* __restrict__ enc, const unsigned short* __restrict__ WeT,
    const float* __restrict__ Wo, const float* __restrict__ dp,
    float* __restrict__ parts) {
    __shared__ unsigned short sA[BM * LDA];
    __shared__ unsigned short sB[BN * LDA];
    __shared__ float sRed[2][BM];

    int tid = threadIdx.x;
    int nt = blockIdx.x & 3;
    int mt = blockIdx.x >> 2;
    int m0 = mt * BM;
    int n0 = nt * BN;
    int b = m0 >> 12;  // m0 / 4096
    int wave = tid >> 6, lane = tid & 63;
    int wm = wave & 1, wn = wave >> 1;
    int quad = lane >> 4, l16 = lane & 15;

    f32x4 acc[4][4];
#pragma unroll
    for (int i = 0; i < 4; ++i)
#pragma unroll
        for (int j = 0; j < 4; ++j) acc[i][j] = (f32x4)0.f;

    // A staging: pass p: row m = p*32 + (tid>>3), k-off c = (tid&7)*4
    int am = tid >> 3;
    int ac = (tid & 7) * 4;
    const float* encP = enc + (size_t)(m0 + am) * E_ + ac;
    unsigned short* sAp = sA + am * LDA + ac;
    // B staging: row n = tid>>1, k-half = tid&1 (16 bf16 each)
    int bn = tid >> 1, bh = tid & 1;
    const unsigned short* wtP = WeT + (size_t)(n0 + bn) * E_ + bh * 16;
    unsigned short* sBp = sB + bn * LDA + bh * 16;

    int aBase = (wm * 64 + l16) * LDA + quad * 8;
    int bBase = (wn * 64 + l16) * LDA + quad * 8;

    for (int k0 = 0; k0 < E_; k0 += BK) {
        __syncthreads();
        // stage A: 128x32 fp32 -> bf16
#pragma unroll
        for (int p = 0; p < 4; ++p) {
            float4 v = *(const float4*)(encP + (size_t)p * 32 * E_ + k0);
            ushort4 u;
            u.x = f2bf(v.x); u.y = f2bf(v.y); u.z = f2bf(v.z); u.w = f2bf(v.w);
            *(ushort4*)(sAp + p * 32 * LDA) = u;
        }
        // stage B: 128x32 bf16 from WeT
        u16x8 w0 = *(const u16x8*)(wtP + k0);
        u16x8 w1 = *(const u16x8*)(wtP + k0 + 8);
        *(u16x8*)(sBp) = w0;
        *(u16x8*)(sBp + 8) = w1;
        __syncthreads();

        bf16x8 aR[4], bR[4];
#pragma unroll
        for (int i = 0; i < 4; ++i) aR[i] = *(const bf16x8*)(sA + aBase + i * 16 * LDA);
#pragma unroll
        for (int j = 0; j < 4; ++j) bR[j] = *(const bf16x8*)(sB + bBase + j * 16 * LDA);
#pragma unroll
        for (int i = 0; i < 4; ++i)
#pragma unroll
            for (int j = 0; j < 4; ++j)
                acc[i][j] = __builtin_amdgcn_mfma_f32_16x16x32_bf16(aR[i], bR[j], acc[i][j], 0, 0, 0);
    }

    // Epilogue: tanh(acc + dp) * Wo, reduce over h
    float dpv[4], wov[4];
#pragma unroll
    for (int j = 0; j < 4; ++j) {
        int h = n0 + wn * 64 + j * 16 + l16;
        dpv[j] = dp[b * H_ + h];
        wov[j] = Wo[h];
    }
    float part[4][4];
#pragma unroll
    for (int i = 0; i < 4; ++i)
#pragma unroll
        for (int r = 0; r < 4; ++r) {
            float s = 0.f;
#pragma unroll
            for (int j = 0; j < 4; ++j) {
                float x = acc[i][j][r] + dpv[j];
                float e = __expf(2.f * x);
                s += (1.f - 2.f / (e + 1.f)) * wov[j];
            }
            part[i][r] = s;
        }
#pragma unroll
    for (int i = 0; i < 4; ++i)
#pragma unroll
        for (int r = 0; r < 4; ++r) {
            float s = part[i][r];
            s += __shfl_xor(s, 1, 64);
            s += __shfl_xor(s, 2, 64);
            s += __shfl_xor(s, 4, 64);
            s += __shfl_xor(s, 8, 64);
            part[i][r] = s;
        }
    if (l16 == 0) {
#pragma unroll
        for (int i = 0; i < 4; ++i)
#pragma unroll
            for (int r = 0; r < 4; ++r)
                sRed[wn][wm * 64 + i * 16 + quad * 4 + r] = part[i][r];
    }
    __syncthreads();
    if (tid < BM) {
        float sc = sRed[0][tid] + sRed[1][tid];
        int s = (m0 & (S_ - 1)) + tid;
        parts[(size_t)(nt * B_ + b) * S_ + s] = sc;
    }
}

// softmax over S per batch row; input = 4 partial score buffers, output into parts[0]
__global__ __launch_bounds__(256) void softmax_kernel(float* __restrict__ parts) {
    int b = blockIdx.x;
    const float* p0 = parts + (size_t)(0 * B_ + b) * S_;
    const float* p1 = parts + (size_t)(1 * B_ + b) * S_;
    const float* p2 = parts + (size_t)(2 * B_ + b) * S_;
    const float* p3 = parts + (size_t)(3 * B_ + b) * S_;
    float* row = parts + (size_t)b * S_;
    int tid = threadIdx.x;
    float v[16];
    float m = -1e30f;
#pragma unroll
    for (int i = 0; i < 16; ++i) {
        int idx = i * 256 + tid;
        v[i] = p0[idx] + p1[idx] + p2[idx] + p3[idx];
        m = fmaxf(m, v[i]);
    }
    for (int off = 32; off; off >>= 1) m = fmaxf(m, __shfl_xor(m, off, 64));
    __shared__ float redm[4];
    __shared__ float reds[4];
    if ((tid & 63) == 0) redm[tid >> 6] = m;
    __syncthreads();
    m = fmaxf(fmaxf(redm[0], redm[1]), fmaxf(redm[2], redm[3]));
    float s = 0.f;
#pragma unroll
    for (int i = 0; i < 16; ++i) {
        v[i] = __expf(v[i] - m);
        s += v[i];
    }
    for (int off = 32; off; off >>= 1) s += __shfl_xor(s, off, 64);
    if ((tid & 63) == 0) reds[tid >> 6] = s;
    __syncthreads();
    s = reds[0] + reds[1] + reds[2] + reds[3];
    float inv = 1.f / s;
#pragma unroll
    for (int i = 0; i < 16; ++i) row[i * 256 + tid] = v[i] * inv;
}

__global__ __launch_bounds__(256) void zero_kernel(float* __restrict__ out) {
    out[blockIdx.x * 256 + threadIdx.x] = 0.f;
}

// context[b][e] = sum_s attn[b][s] * enc[b][s][e]
__global__ __launch_bounds__(256) void ctx_kernel(const float* __restrict__ enc,
                                                  const float* __restrict__ attn,
                                                  float* __restrict__ out) {
    int b = blockIdx.x >> 5;
    int s0 = (blockIdx.x & 31) * 128;
    int tid = threadIdx.x;
    __shared__ float w[128];
    if (tid < 128) w[tid] = attn[(size_t)b * S_ + s0 + tid];
    __syncthreads();
    const float* base = enc + ((size_t)b * S_ + s0) * E_ + tid * 4;
    float4 acc = make_float4(0.f, 0.f, 0.f, 0.f);
    for (int s = 0; s < 128; ++s) {
        float4 v = *(const float4*)(base + (size_t)s * E_);
        float ws = w[s];
        acc.x = fmaf(ws, v.x, acc.x);
        acc.y = fmaf(ws, v.y, acc.y);
        acc.z = fmaf(ws, v.z, acc.z);
        acc.w = fmaf(ws, v.w, acc.w);
    }
    float* o = out + b * E_ + tid * 4;
    atomicAdd(o + 0, acc.x);
    atomicAdd(o + 1, acc.y);
    atomicAdd(o + 2, acc.z);
    atomicAdd(o + 3, acc.w);
}

extern "C" void kernel_launch(void* const* d_in, const int* in_sizes, int n_in,
                              void* d_out, int out_size, void* d_ws, size_t ws_size,
                              hipStream_t stream) {
    const float* enc = (const float*)d_in[0];  // [16,4096,1024]
    const float* dec = (const float*)d_in[1];  // [16,1024]
    const float* We  = (const float*)d_in[2];  // [1024,512]
    const float* be  = (const float*)d_in[3];  // [512]
    const float* Wd  = (const float*)d_in[4];  // [1024,512]
    const float* bd  = (const float*)d_in[5];  // [512]
    const float* Wo  = (const float*)d_in[6];  // [512,1]
    float* out = (float*)d_out;                // [16,1024]

    char* w = (char*)d_ws;
    unsigned short* WeT = (unsigned short*)w;              // 512*1024 bf16 = 1 MiB
    float* dp = (float*)(w + (1 << 20));                   // 16*512 fp32 = 32 KB
    float* parts = (float*)(w + (1 << 20) + 32768);        // 4*16*4096 fp32 = 1 MiB
    float* attn = parts;                                   // softmax writes into part 0

    we_transpose_kernel<<<128, 256, 0, stream>>>(We, WeT);
    dp_kernel<<<B_ * 8, 256, 0, stream>>>(dec, Wd, bd, be, dp);
    scores_mfma_kernel<<<(B_ * S_ / BM) * (H_ / BN), 256, 0, stream>>>(enc, WeT, Wo, dp, parts);
    softmax_kernel<<<B_, 256, 0, stream>>>(parts);
    zero_kernel<<<(B_ * E_) / 256, 256, 0, stream>>>(out);
    ctx_kernel<<<B_ * 32, 256, 0, stream>>>(enc, attn, out);
}